// Round 7
// baseline (738.235 us; speedup 1.0000x reference)
//
#include <hip/hip_runtime.h>
#include <math.h>

#define NN 20480
#define NE 327680
#define NBATCH 16
#define NBLK 240                      // <= CU count (256) with margin: residency guaranteed
#define NTHR 1024
#define GSZ (NBLK * NTHR)             // 245760
#define NWAVE (NBLK * (NTHR / 64))    // 3840
#define NPB ((NN + NBLK - 1) / NBLK)  // 86 counts per block in scan

typedef float v2f __attribute__((ext_vector_type(2)));

static __device__ __forceinline__ v2f vmax0(v2f a) {
  v2f r; r.x = fmaxf(a.x, 0.f); r.y = fmaxf(a.y, 0.f); return r;
}

struct Args {
  const float* x; const int* src; const int* dst; const int* etype;
  const float* eattr; const int* ct;
  const float* emb[4]; const float* wh[4]; const float* bh[4];
  const float* wg[4]; const float* bg[4]; const float* root[4]; const float* bias[4];
  const float* clf_w; const float* clf_b;
  float* out;
  int* off; float4* es; float* hA; float* hB; float* h4;
  float* eT1; float* eT2; float* eT3; float* eT4;
  float* pooled; float* pcnt; int* cnt; int* cur; int* bar; int* partial;
};

// ---- device-scope grid barrier (sense via generation counter) --------------
// All NBLK blocks are co-resident by construction (grid <= CUs, VGPR<=128).
__device__ __forceinline__ void grid_sync(int* cntp, int* genp) {
  __syncthreads();
  if (threadIdx.x == 0) {
    __threadfence();                                        // release our writes
    int g = __hip_atomic_load(genp, __ATOMIC_RELAXED, __HIP_MEMORY_SCOPE_AGENT);
    int c = __hip_atomic_fetch_add(cntp, 1, __ATOMIC_ACQ_REL, __HIP_MEMORY_SCOPE_AGENT);
    if (c == NBLK - 1) {
      __hip_atomic_store(cntp, 0, __ATOMIC_RELAXED, __HIP_MEMORY_SCOPE_AGENT);
      __hip_atomic_store(genp, g + 1, __ATOMIC_RELEASE, __HIP_MEMORY_SCOPE_AGENT);
    } else {
      while (__hip_atomic_load(genp, __ATOMIC_ACQUIRE, __HIP_MEMORY_SCOPE_AGENT) == g)
        __builtin_amdgcn_s_sleep(4);
    }
    __threadfence();                                        // acquire remote writes
  }
  __syncthreads();
}

// ---- layer 1: cin=16, cout=8. lane=(esub<<4)|(ihalf<<3)|o ------------------
__device__ __forceinline__ void do_small16(const Args& a) {
  const int D = 128;
  int lane = threadIdx.x & 63;
  int o = lane & 7, ihalf = (lane >> 3) & 1, esub = lane >> 4;
  int ibase = ihalf * 8;
  const float *wh = a.wh[0], *bh = a.bh[0], *wg = a.wg[0], *bg = a.bg[0];
  const float *root = a.root[0], *bias = a.bias[0];
  v2f rwh0[4], rwh1[4], rbh[4], rwg0[4], rwg1[4], rbg[4], rroot[4];
#pragma unroll
  for (int p = 0; p < 4; p++) {
    int ai = (ibase + 2 * p) * 8 + o, bi = (ibase + 2 * p + 1) * 8 + o;
    rwh0[p] = (v2f){wh[ai], wh[bi]};  rwh1[p] = (v2f){wh[D + ai], wh[D + bi]};
    rbh[p]  = (v2f){bh[ai], bh[bi]};
    rwg0[p] = (v2f){wg[ai], wg[bi]};  rwg1[p] = (v2f){wg[D + ai], wg[D + bi]};
    rbg[p]  = (v2f){bg[ai], bg[bi]};  rroot[p] = (v2f){root[ai], root[bi]};
  }
  float rbias = bias[o];
  int wid = blockIdx.x * (NTHR / 64) + (threadIdx.x >> 6);
  for (int n0 = wid; n0 < NN; n0 += NWAVE) {
    int n = __builtin_amdgcn_readfirstlane(n0);
    int beg = a.off[n], end = a.off[n + 1];
    float acc = 0.f;
    int j = beg + esub;
    bool v0 = j < end;
    float4 rec0 = v0 ? a.es[j] : make_float4(0.f, 0.f, 0.f, 0.f);
    int s0 = __float_as_int(rec0.x);
    const float4* hp0 = (const float4*)(a.x + s0 * 16 + ibase);
    float4 hA0 = hp0[0], hB0 = hp0[1];
    while (__ballot(v0)) {
      int j1 = j + 4;
      bool v1 = j1 < end;
      float4 rec1 = v1 ? a.es[j1] : make_float4(0.f, 0.f, 0.f, 0.f);
      int s1 = __float_as_int(rec1.x);
      const float4* hp1 = (const float4*)(a.x + s1 * 16 + ibase);
      float4 hA1 = hp1[0], hB1 = hp1[1];
      int t0 = __float_as_int(rec0.y);
      const float4* sp = (const float4*)(a.eT1 + t0 * 128 + o * 16 + ibase);
      float4 sv0 = sp[0], sv1 = sp[1];
      v2f stv[4] = {(v2f){sv0.x, sv0.y}, (v2f){sv0.z, sv0.w},
                    (v2f){sv1.x, sv1.y}, (v2f){sv1.z, sv1.w}};
      v2f hv[4] = {(v2f){hA0.x, hA0.y}, (v2f){hA0.z, hA0.w},
                   (v2f){hB0.x, hB0.y}, (v2f){hB0.z, hB0.w}};
      v2f ef0 = (v2f){rec0.z, rec0.z}, ef1 = (v2f){rec0.w, rec0.w};
      v2f msg = {0.f, 0.f};
#pragma unroll
      for (int p = 0; p < 4; p++) {
        v2f hval = ef0 * rwh0[p] + ef1 * rwh1[p] + rbh[p];
        v2f gval = ef0 * rwg0[p] + ef1 * rwg1[p] + rbg[p];
        msg += hv[p] * vmax0(stv[p] * hval + gval);
      }
      acc += v0 ? (msg.x + msg.y) : 0.f;
      rec0 = rec1; hA0 = hA1; hB0 = hB1; v0 = v1; j = j1;
    }
    acc += __shfl_xor(acc, 8);
    acc += __shfl_xor(acc, 16);
    acc += __shfl_xor(acc, 32);
    const float* hn = a.x + n * 16 + ibase;
    v2f rtv = {0.f, 0.f};
#pragma unroll
    for (int p = 0; p < 4; p++)
      rtv += (v2f){hn[2 * p], hn[2 * p + 1]} * rroot[p];
    float rt = rtv.x + rtv.y;
    rt += __shfl_xor(rt, 8);
    float deg = (float)(end - beg);
    float val = fmaxf(rbias + rt + acc / fmaxf(deg, 1.f), 0.f);
    if (lane < 8) a.hA[n * 8 + o] = val;
  }
}

// ---- cin=8, cout=8 layers (L2,L3). lane=(esub<<3)|o ------------------------
__device__ __forceinline__ void do_small8(
    const int* __restrict__ off, const float4* __restrict__ es,
    const float* __restrict__ h_in, const float* __restrict__ embT,
    const float* __restrict__ wh, const float* __restrict__ bh,
    const float* __restrict__ wg, const float* __restrict__ bg,
    const float* __restrict__ root, const float* __restrict__ bias,
    float* __restrict__ h_out) {
  int lane = threadIdx.x & 63;
  int o = lane & 7, esub = lane >> 3;
  v2f rwh0[4], rwh1[4], rbh[4], rwg0[4], rwg1[4], rbg[4], rroot[4];
#pragma unroll
  for (int p = 0; p < 4; p++) {
    int ai = (2 * p) * 8 + o, bi = (2 * p + 1) * 8 + o;
    rwh0[p] = (v2f){wh[ai], wh[bi]};  rwh1[p] = (v2f){wh[64 + ai], wh[64 + bi]};
    rbh[p]  = (v2f){bh[ai], bh[bi]};
    rwg0[p] = (v2f){wg[ai], wg[bi]};  rwg1[p] = (v2f){wg[64 + ai], wg[64 + bi]};
    rbg[p]  = (v2f){bg[ai], bg[bi]};  rroot[p] = (v2f){root[ai], root[bi]};
  }
  float rbias = bias[o];
  int wid = blockIdx.x * (NTHR / 64) + (threadIdx.x >> 6);
  for (int n0 = wid; n0 < NN; n0 += NWAVE) {
    int n = __builtin_amdgcn_readfirstlane(n0);
    int beg = off[n], end = off[n + 1];
    float acc = 0.f;
    int j = beg + esub;
    bool v0 = j < end;
    float4 rec0 = v0 ? es[j] : make_float4(0.f, 0.f, 0.f, 0.f);
    int s0 = __float_as_int(rec0.x);
    const float4* hp0 = (const float4*)(h_in + s0 * 8);
    float4 hA0 = hp0[0], hB0 = hp0[1];
    while (__ballot(v0)) {
      int j1 = j + 8;
      bool v1 = j1 < end;
      float4 rec1 = v1 ? es[j1] : make_float4(0.f, 0.f, 0.f, 0.f);
      int s1 = __float_as_int(rec1.x);
      const float4* hp1 = (const float4*)(h_in + s1 * 8);
      float4 hA1 = hp1[0], hB1 = hp1[1];
      int t0 = __float_as_int(rec0.y);
      const float4* sp = (const float4*)(embT + t0 * 64 + o * 8);
      float4 sv0 = sp[0], sv1 = sp[1];
      v2f stv[4] = {(v2f){sv0.x, sv0.y}, (v2f){sv0.z, sv0.w},
                    (v2f){sv1.x, sv1.y}, (v2f){sv1.z, sv1.w}};
      v2f hv[4] = {(v2f){hA0.x, hA0.y}, (v2f){hA0.z, hA0.w},
                   (v2f){hB0.x, hB0.y}, (v2f){hB0.z, hB0.w}};
      v2f ef0 = (v2f){rec0.z, rec0.z}, ef1 = (v2f){rec0.w, rec0.w};
      v2f msg = {0.f, 0.f};
#pragma unroll
      for (int p = 0; p < 4; p++) {
        v2f hval = ef0 * rwh0[p] + ef1 * rwh1[p] + rbh[p];
        v2f gval = ef0 * rwg0[p] + ef1 * rwg1[p] + rbg[p];
        msg += hv[p] * vmax0(stv[p] * hval + gval);
      }
      acc += v0 ? (msg.x + msg.y) : 0.f;
      rec0 = rec1; hA0 = hA1; hB0 = hB1; v0 = v1; j = j1;
    }
    acc += __shfl_xor(acc, 8);
    acc += __shfl_xor(acc, 16);
    acc += __shfl_xor(acc, 32);
    const float* hn = h_in + n * 8;
    v2f rtv = {0.f, 0.f};
#pragma unroll
    for (int p = 0; p < 4; p++)
      rtv += (v2f){hn[2 * p], hn[2 * p + 1]} * rroot[p];
    float deg = (float)(end - beg);
    float val = fmaxf(rbias + rtv.x + rtv.y + acc / fmaxf(deg, 1.f), 0.f);
    if (lane < 8) h_out[n * 8 + o] = val;
  }
}

// ---- layer 4: cin=8, cout=64. 1 node/wave, lane = out channel --------------
__device__ __forceinline__ void do_l4(const Args& a) {
  int lane = threadIdx.x & 63;
  const float *wh = a.wh[3], *bh = a.bh[3], *wg = a.wg[3], *bg = a.bg[3];
  const float *root = a.root[3], *bias = a.bias[3];
  const float* embT = a.eT4;
  const float* h_in = a.hA;
  v2f rwh0[4], rwh1[4], rbh[4], rwg0[4], rwg1[4], rbg[4], rroot[4];
#pragma unroll
  for (int p = 0; p < 4; p++) {
    int ai = (2 * p) * 64 + lane, bi = (2 * p + 1) * 64 + lane;
    rwh0[p] = (v2f){wh[ai], wh[bi]};  rwh1[p] = (v2f){wh[512 + ai], wh[512 + bi]};
    rbh[p]  = (v2f){bh[ai], bh[bi]};
    rwg0[p] = (v2f){wg[ai], wg[bi]};  rwg1[p] = (v2f){wg[512 + ai], wg[512 + bi]};
    rbg[p]  = (v2f){bg[ai], bg[bi]};  rroot[p] = (v2f){root[ai], root[bi]};
  }
  float rbias = bias[lane];
  int wid = blockIdx.x * (NTHR / 64) + (threadIdx.x >> 6);
  for (int n0 = wid; n0 < NN; n0 += NWAVE) {
    int n = __builtin_amdgcn_readfirstlane(n0);
    int beg = a.off[n], end = a.off[n + 1];
    float acc0 = 0.f, acc1 = 0.f;
    int e = beg;
    for (; e + 2 <= end; e += 2) {
      float4 r0 = a.es[e], r1 = a.es[e + 1];
      int s0 = __float_as_int(r0.x), t0 = __float_as_int(r0.y);
      int s1 = __float_as_int(r1.x), t1 = __float_as_int(r1.y);
      const float4* hp0 = (const float4*)(h_in + s0 * 8);
      const float4* hp1 = (const float4*)(h_in + s1 * 8);
      float4 a0 = hp0[0], a1 = hp0[1];
      float4 b0 = hp1[0], b1 = hp1[1];
      const float4* ep0 = (const float4*)(embT + t0 * 512 + lane * 8);
      const float4* ep1 = (const float4*)(embT + t1 * 512 + lane * 8);
      float4 s00 = ep0[0], s01 = ep0[1];
      float4 s10 = ep1[0], s11 = ep1[1];
      v2f sv0[4] = {(v2f){s00.x, s00.y}, (v2f){s00.z, s00.w},
                    (v2f){s01.x, s01.y}, (v2f){s01.z, s01.w}};
      v2f sv1[4] = {(v2f){s10.x, s10.y}, (v2f){s10.z, s10.w},
                    (v2f){s11.x, s11.y}, (v2f){s11.z, s11.w}};
      v2f hva[4] = {(v2f){a0.x, a0.y}, (v2f){a0.z, a0.w},
                    (v2f){a1.x, a1.y}, (v2f){a1.z, a1.w}};
      v2f hvb[4] = {(v2f){b0.x, b0.y}, (v2f){b0.z, b0.w},
                    (v2f){b1.x, b1.y}, (v2f){b1.z, b1.w}};
      v2f e00 = (v2f){r0.z, r0.z}, e01 = (v2f){r0.w, r0.w};
      v2f e10 = (v2f){r1.z, r1.z}, e11 = (v2f){r1.w, r1.w};
      v2f m0 = {0.f, 0.f}, m1 = {0.f, 0.f};
#pragma unroll
      for (int p = 0; p < 4; p++) {
        v2f hv0 = e00 * rwh0[p] + e01 * rwh1[p] + rbh[p];
        v2f gv0 = e00 * rwg0[p] + e01 * rwg1[p] + rbg[p];
        m0 += hva[p] * vmax0(sv0[p] * hv0 + gv0);
        v2f hv1 = e10 * rwh0[p] + e11 * rwh1[p] + rbh[p];
        v2f gv1 = e10 * rwg0[p] + e11 * rwg1[p] + rbg[p];
        m1 += hvb[p] * vmax0(sv1[p] * hv1 + gv1);
      }
      acc0 += m0.x + m0.y;
      acc1 += m1.x + m1.y;
    }
    if (e < end) {
      float4 r0 = a.es[e];
      int s0 = __float_as_int(r0.x), t0 = __float_as_int(r0.y);
      const float4* hp0 = (const float4*)(h_in + s0 * 8);
      float4 a0 = hp0[0], a1 = hp0[1];
      const float4* ep0 = (const float4*)(embT + t0 * 512 + lane * 8);
      float4 s00 = ep0[0], s01 = ep0[1];
      v2f sv0[4] = {(v2f){s00.x, s00.y}, (v2f){s00.z, s00.w},
                    (v2f){s01.x, s01.y}, (v2f){s01.z, s01.w}};
      v2f hva[4] = {(v2f){a0.x, a0.y}, (v2f){a0.z, a0.w},
                    (v2f){a1.x, a1.y}, (v2f){a1.z, a1.w}};
      v2f e00 = (v2f){r0.z, r0.z}, e01 = (v2f){r0.w, r0.w};
      v2f m0 = {0.f, 0.f};
#pragma unroll
      for (int p = 0; p < 4; p++) {
        v2f hv0 = e00 * rwh0[p] + e01 * rwh1[p] + rbh[p];
        v2f gv0 = e00 * rwg0[p] + e01 * rwg1[p] + rbg[p];
        m0 += hva[p] * vmax0(sv0[p] * hv0 + gv0);
      }
      acc0 += m0.x + m0.y;
    }
    float acc = acc0 + acc1;
    float deg = (float)(end - beg);
    const float* hn = h_in + n * 8;
    v2f rtv = {0.f, 0.f};
#pragma unroll
    for (int p = 0; p < 4; p++)
      rtv += (v2f){hn[2 * p], hn[2 * p + 1]} * rroot[p];
    a.h4[n * 64 + lane] = fmaxf(rbias + rtv.x + rtv.y + acc / fmaxf(deg, 1.f), 0.f);
  }
}

// ---- the whole network in one persistent kernel ----------------------------
__global__ __launch_bounds__(NTHR, 4) void mega_kernel(Args a) {
  int t = threadIdx.x;
  int gtid = blockIdx.x * NTHR + t;
  int* bcnt = a.bar;
  int* bgen = a.bar + 1;

  // P0: zero cnt/pooled/pcnt + transpose emb tables to [t][o][i]
  if (gtid < NN) a.cnt[gtid] = 0;
  if (gtid < NBATCH * 64 + NBATCH) a.pooled[gtid] = 0.f;   // pooled then pcnt (contiguous)
  if (gtid < 36 * 128) {
    int tt = gtid >> 7, r = gtid & 127, o = r >> 4, i = r & 15;
    a.eT1[gtid] = a.emb[0][(tt << 7) + i * 8 + o];
  }
  if (gtid < 36 * 64) {
    int tt = gtid >> 6, r = gtid & 63, o = r >> 3, i = r & 7;
    a.eT2[gtid] = a.emb[1][(tt << 6) + i * 8 + o];
    a.eT3[gtid] = a.emb[2][(tt << 6) + i * 8 + o];
  }
  if (gtid < 36 * 512) {
    int tt = gtid >> 9, r = gtid & 511, o = r >> 3, i = r & 7;
    a.eT4[gtid] = a.emb[3][(tt << 9) + i * 64 + o];
  }
  grid_sync(bcnt, bgen);

  // P1: degree histogram
  for (int e = gtid; e < NE; e += GSZ) atomicAdd(&a.cnt[a.dst[e]], 1);
  grid_sync(bcnt, bgen);

  // P2: block-local exclusive scan over NPB counts, write partial totals
  {
    __shared__ int sA[128];
    int base = blockIdx.x * NPB;
    int c = 0;
    if (t < NPB && base + t < NN) c = a.cnt[base + t];
    if (t < 128) sA[t] = (t < NPB) ? c : 0;
    __syncthreads();
    for (int d = 1; d < 128; d <<= 1) {
      int v = 0;
      if (t < 128 && t >= d) v = sA[t - d];
      __syncthreads();
      if (t < 128) sA[t] += v;
      __syncthreads();
    }
    if (t < NPB && base + t < NN) a.off[base + t] = sA[t] - c;  // local exclusive
    if (t == 0) a.partial[blockIdx.x] = sA[127];                // block total
  }
  grid_sync(bcnt, bgen);

  // P3: every block scans partial[NBLK] redundantly, finalizes off/cur
  {
    __shared__ int sB[NBLK];
    if (t < NBLK) sB[t] = a.partial[t];
    __syncthreads();
    for (int d = 1; d < NBLK; d <<= 1) {
      int v = 0;
      if (t < NBLK && t >= d) v = sB[t - d];
      __syncthreads();
      if (t < NBLK) sB[t] += v;
      __syncthreads();
    }
    int pre = (blockIdx.x == 0) ? 0 : sB[blockIdx.x - 1];
    int base = blockIdx.x * NPB;
    if (t < NPB && base + t < NN) {
      int v = a.off[base + t] + pre;
      a.off[base + t] = v;
      a.cur[base + t] = v;
    }
    if (blockIdx.x == 0 && t == 0) a.off[NN] = NE;
  }
  grid_sync(bcnt, bgen);

  // P4: scatter edges into dst-sorted records
  for (int e = gtid; e < NE; e += GSZ) {
    int d = a.dst[e];
    int pos = atomicAdd(&a.cur[d], 1);
    a.es[pos] = make_float4(__int_as_float(a.src[e]), __int_as_float(a.etype[e]),
                            a.eattr[2 * e], a.eattr[2 * e + 1]);
  }
  grid_sync(bcnt, bgen);

  // P5..P8: four fused layers with grid-wide sync between
  do_small16(a);                                           // x   -> hA
  grid_sync(bcnt, bgen);
  do_small8(a.off, a.es, a.hA, a.eT2, a.wh[1], a.bh[1], a.wg[1], a.bg[1],
            a.root[1], a.bias[1], a.hB);                   // hA -> hB
  grid_sync(bcnt, bgen);
  do_small8(a.off, a.es, a.hB, a.eT3, a.wh[2], a.bh[2], a.wg[2], a.bg[2],
            a.root[2], a.bias[2], a.hA);                   // hB -> hA
  grid_sync(bcnt, bgen);
  do_l4(a);                                                // hA -> h4
  grid_sync(bcnt, bgen);

  // P9: gated pooling partials (320 units of 64 nodes; grid-stride)
  {
    __shared__ float ss[16][64];
    __shared__ float scn[16];
    int o = t & 63, sub = t >> 6;
    for (int u = blockIdx.x; u < NBATCH * 20; u += NBLK) {
      int b = u / 20, c = u % 20;
      int base = b * (NN / NBATCH) + c * 64;
      float sum = 0.f, cntf = 0.f;
      for (int j = sub; j < 64; j += 16) {
        int n = base + j;
        if (a.ct[n] == 1) { sum += a.h4[n * 64 + o]; cntf += 1.f; }
      }
      ss[sub][o] = sum;
      if (o == 0) scn[sub] = cntf;
      __syncthreads();
      if (t < 64) {
        float tot = 0.f;
#pragma unroll
        for (int k = 0; k < 16; k++) tot += ss[k][o];
        unsafeAtomicAdd(&a.pooled[b * 64 + o], tot);
        if (o == 0) {
          float cc = 0.f;
#pragma unroll
          for (int k = 0; k < 16; k++) cc += scn[k];
          unsafeAtomicAdd(&a.pcnt[b], cc);
        }
      }
      __syncthreads();
    }
  }
  grid_sync(bcnt, bgen);

  // P10: classifier + sigmoid (block 0; one wave per batch)
  if (blockIdx.x == 0) {
    int b = t >> 6, o = t & 63;
    float c = a.pcnt[b];
    float v = (a.pooled[b * 64 + o] / fmaxf(c, 1.f)) * a.clf_w[o];
#pragma unroll
    for (int d = 32; d; d >>= 1) v += __shfl_down(v, d);
    if (o == 0) a.out[b] = 1.f / (1.f + expf(-(v + a.clf_b[0])));
  }
}

// ---------------------------------------------------------------------------
extern "C" void kernel_launch(void* const* d_in, const int* in_sizes, int n_in,
                              void* d_out, int out_size, void* d_ws, size_t ws_size,
                              hipStream_t stream) {
  (void)in_sizes; (void)n_in; (void)out_size; (void)ws_size;
  Args a;
  a.x     = (const float*)d_in[0];
  const int* eidx = (const int*)d_in[1];
  a.src   = eidx;
  a.dst   = eidx + NE;
  a.etype = (const int*)d_in[2];
  a.eattr = (const float*)d_in[3];
  a.ct    = (const int*)d_in[4];
  for (int l = 0; l < 4; l++) {
    int b0 = 6 + 7 * l;
    a.emb[l]  = (const float*)d_in[b0 + 0];
    a.wh[l]   = (const float*)d_in[b0 + 1];
    a.bh[l]   = (const float*)d_in[b0 + 2];
    a.wg[l]   = (const float*)d_in[b0 + 3];
    a.bg[l]   = (const float*)d_in[b0 + 4];
    a.root[l] = (const float*)d_in[b0 + 5];
    a.bias[l] = (const float*)d_in[b0 + 6];
  }
  a.clf_w = (const float*)d_in[34];
  a.clf_b = (const float*)d_in[35];
  a.out   = (float*)d_out;

  // workspace layout (floats): ~12.0 MB
  float* ws = (float*)d_ws;
  a.off    = (int*)ws;                        // 20484 (NN+1 padded)
  a.es     = (float4*)(ws + 20484);           // NE float4 (16B-aligned: 81936 % 16 == 0)
  a.hA     = ws + 20484 + 4 * NE;             // 8N
  a.hB     = a.hA + 8 * NN;                   // 8N
  a.h4     = a.hB + 8 * NN;                   // 64N
  a.eT1    = a.h4 + 64 * NN;                  // 36*128
  a.eT2    = a.eT1 + 36 * 128;                // 36*64
  a.eT3    = a.eT2 + 36 * 64;                 // 36*64
  a.eT4    = a.eT3 + 36 * 64;                 // 36*512
  a.pooled = a.eT4 + 36 * 512;                // 16*64 (+16 pcnt contiguous)
  a.pcnt   = a.pooled + NBATCH * 64;          // 16
  a.bar    = (int*)(a.pcnt + NBATCH);         // 2
  a.partial= a.bar + 2;                       // NBLK
  a.cnt    = (int*)a.h4;                      // alias (h4 dead until P8)
  a.cur    = a.cnt + NN;                      // alias

  // barrier state must be zero at kernel start (ws is poisoned 0xAA)
  hipMemsetAsync(a.bar, 0, 2 * sizeof(int), stream);
  mega_kernel<<<NBLK, NTHR, 0, stream>>>(a);
}

// Round 8
// 335.909 us; speedup vs baseline: 2.1977x; 2.1977x over previous
//
#include <hip/hip_runtime.h>
#include <math.h>

#define NN 20480
#define NE 327680
#define NBATCH 16

typedef float v2f __attribute__((ext_vector_type(2)));

static __device__ __forceinline__ v2f vmax0(v2f a) {
  v2f r; r.x = fmaxf(a.x, 0.f); r.y = fmaxf(a.y, 0.f); return r;
}

// ---------------- prep: histogram + emb transpose (fused) -------------------
__global__ __launch_bounds__(256) void prep_kernel(
    const int* __restrict__ dst, int* __restrict__ cnt,
    const float* __restrict__ e1, const float* __restrict__ e2,
    const float* __restrict__ e3, const float* __restrict__ e4,
    float* __restrict__ t1, float* __restrict__ t2,
    float* __restrict__ t3, float* __restrict__ t4) {
  int b = blockIdx.x;
  if (b < NE / 256) {
    int e = b * 256 + threadIdx.x;
    atomicAdd(&cnt[dst[e]], 1);
  } else {
    int idx = (b - NE / 256) * 256 + threadIdx.x;   // 0 .. 18431
    if (idx < 36 * 128) {
      int t = idx >> 7, r = idx & 127, o = r >> 4, i = r & 15;
      t1[idx] = e1[(t << 7) + i * 8 + o];
    }
    if (idx < 36 * 64) {
      int t = idx >> 6, r = idx & 63, o = r >> 3, i = r & 7;
      t2[idx] = e2[(t << 6) + i * 8 + o];
      t3[idx] = e3[(t << 6) + i * 8 + o];
    }
    {
      int t = idx >> 9, r = idx & 511, o = r >> 3, i = r & 7;
      t4[idx] = e4[(t << 9) + i * 64 + o];
    }
  }
}

// ------- exclusive scan over NN counts (1 block); writes off AND cur --------
__global__ __launch_bounds__(1024) void scan_kernel(const int* __restrict__ cnt,
                                                    int* __restrict__ off,
                                                    int* __restrict__ cur,
                                                    float* __restrict__ poolz) {
  __shared__ int part[1024];
  int tid = threadIdx.x;
  if (tid < 16 * 64 + 16) poolz[tid] = 0.f;
  const int PT = NN / 1024;              // 20 per thread
  int loc[PT];
  int run = 0;
  int base = tid * PT;
#pragma unroll
  for (int k = 0; k < PT; k++) { loc[k] = run; run += cnt[base + k]; }
  part[tid] = run;
  __syncthreads();
  for (int d = 1; d < 1024; d <<= 1) {
    int t = (tid >= d) ? part[tid - d] : 0;
    __syncthreads();
    part[tid] += t;
    __syncthreads();
  }
  int pre = (tid == 0) ? 0 : part[tid - 1];
#pragma unroll
  for (int k = 0; k < PT; k++) {
    off[base + k] = pre + loc[k];
    cur[base + k] = pre + loc[k];
  }
  if (tid == 1023) off[NN] = pre + run;  // == NE
}

__global__ void scatter_kernel(const int* __restrict__ src, const int* __restrict__ dst,
                               const int* __restrict__ etype, const float* __restrict__ eattr,
                               int* __restrict__ cur, float4* __restrict__ es) {
  int e = blockIdx.x * blockDim.x + threadIdx.x;
  if (e >= NE) return;
  int d = dst[e];
  int pos = atomicAdd(&cur[d], 1);
  es[pos] = make_float4(__int_as_float(src[e]), __int_as_float(etype[e]),
                        eattr[2 * e], eattr[2 * e + 1]);
}

// ---------------- fused layer 1 (cin=16, cout=8) ----------------------------
__global__ __launch_bounds__(256) void layer_small16(
    const int* __restrict__ off, const float4* __restrict__ es,
    const float* __restrict__ h_in, const float* __restrict__ embT,
    const float* __restrict__ wh, const float* __restrict__ bh,
    const float* __restrict__ wg, const float* __restrict__ bg,
    const float* __restrict__ root, const float* __restrict__ bias,
    float* __restrict__ h_out) {
  constexpr int D = 128;
  int lane = threadIdx.x & 63;
  int o = lane & 7;
  int ihalf = (lane >> 3) & 1;
  int esub = lane >> 4;                  // 0..3
  int ibase = ihalf * 8;
  v2f rwh0[4], rwh1[4], rbh[4], rwg0[4], rwg1[4], rbg[4], rroot[4];
#pragma unroll
  for (int p = 0; p < 4; p++) {
    int a = (ibase + 2 * p) * 8 + o, b = (ibase + 2 * p + 1) * 8 + o;
    rwh0[p] = (v2f){wh[a], wh[b]};
    rwh1[p] = (v2f){wh[D + a], wh[D + b]};
    rbh[p]  = (v2f){bh[a], bh[b]};
    rwg0[p] = (v2f){wg[a], wg[b]};
    rwg1[p] = (v2f){wg[D + a], wg[D + b]};
    rbg[p]  = (v2f){bg[a], bg[b]};
    rroot[p] = (v2f){root[a], root[b]};
  }
  float rbias = bias[o];
  int n = __builtin_amdgcn_readfirstlane((int)(blockIdx.x * 4) + (int)(threadIdx.x >> 6));
  int beg = off[n], end = off[n + 1];
  float acc = 0.f;
  int j = beg + esub;
  bool val0 = j < end;
  float4 rec0 = val0 ? es[j] : make_float4(0.f, 0.f, 0.f, 0.f);
  int s0 = __float_as_int(rec0.x);
  const float4* hp0 = (const float4*)(h_in + s0 * 16 + ibase);
  float4 hA0 = hp0[0], hB0 = hp0[1];
  while (__ballot(val0)) {
    int j1 = j + 4;
    bool val1 = j1 < end;
    float4 rec1 = val1 ? es[j1] : make_float4(0.f, 0.f, 0.f, 0.f);
    int s1 = __float_as_int(rec1.x);
    const float4* hp1 = (const float4*)(h_in + s1 * 16 + ibase);
    float4 hA1 = hp1[0], hB1 = hp1[1];
    int t0 = __float_as_int(rec0.y);
    const float4* sp = (const float4*)(embT + t0 * 128 + o * 16 + ibase);
    float4 sv0 = sp[0], sv1 = sp[1];
    v2f stv[4] = {(v2f){sv0.x, sv0.y}, (v2f){sv0.z, sv0.w},
                  (v2f){sv1.x, sv1.y}, (v2f){sv1.z, sv1.w}};
    v2f hv[4] = {(v2f){hA0.x, hA0.y}, (v2f){hA0.z, hA0.w},
                 (v2f){hB0.x, hB0.y}, (v2f){hB0.z, hB0.w}};
    v2f ef0 = (v2f){rec0.z, rec0.z}, ef1 = (v2f){rec0.w, rec0.w};
    v2f msg = {0.f, 0.f};
#pragma unroll
    for (int p = 0; p < 4; p++) {
      v2f hval = ef0 * rwh0[p] + ef1 * rwh1[p] + rbh[p];
      v2f gval = ef0 * rwg0[p] + ef1 * rwg1[p] + rbg[p];
      msg += hv[p] * vmax0(stv[p] * hval + gval);
    }
    acc += val0 ? (msg.x + msg.y) : 0.f;
    rec0 = rec1; hA0 = hA1; hB0 = hB1; val0 = val1; j = j1;
  }
  acc += __shfl_xor(acc, 8);
  acc += __shfl_xor(acc, 16);
  acc += __shfl_xor(acc, 32);
  const float* hn = h_in + n * 16 + ibase;
  v2f rtv = {0.f, 0.f};
#pragma unroll
  for (int p = 0; p < 4; p++)
    rtv += (v2f){hn[2 * p], hn[2 * p + 1]} * rroot[p];
  float rt = rtv.x + rtv.y;
  rt += __shfl_xor(rt, 8);
  float deg = (float)(end - beg);
  float val = fmaxf(rbias + rt + acc / fmaxf(deg, 1.f), 0.f);
  if (lane < 8) h_out[n * 8 + o] = val;
}

// ---------------- fused layer, cin=8 cout=8 (L2,L3) -------------------------
__global__ __launch_bounds__(256) void layer_small8(
    const int* __restrict__ off, const float4* __restrict__ es,
    const float* __restrict__ h_in, const float* __restrict__ embT,
    const float* __restrict__ wh, const float* __restrict__ bh,
    const float* __restrict__ wg, const float* __restrict__ bg,
    const float* __restrict__ root, const float* __restrict__ bias,
    float* __restrict__ h_out) {
  int lane = threadIdx.x & 63;
  int o = lane & 7, esub = (lane >> 3) & 3, nsub = lane >> 5;
  v2f rwh0[4], rwh1[4], rbh[4], rwg0[4], rwg1[4], rbg[4], rroot[4];
#pragma unroll
  for (int p = 0; p < 4; p++) {
    int a = (2 * p) * 8 + o, b = (2 * p + 1) * 8 + o;
    rwh0[p] = (v2f){wh[a], wh[b]};
    rwh1[p] = (v2f){wh[64 + a], wh[64 + b]};
    rbh[p]  = (v2f){bh[a], bh[b]};
    rwg0[p] = (v2f){wg[a], wg[b]};
    rwg1[p] = (v2f){wg[64 + a], wg[64 + b]};
    rbg[p]  = (v2f){bg[a], bg[b]};
    rroot[p] = (v2f){root[a], root[b]};
  }
  float rbias = bias[o];
  int wid = (int)(blockIdx.x * 4) + (int)(threadIdx.x >> 6);
  int n = wid * 2 + nsub;                // per-lane node (2 per wave)
  int beg = off[n], end = off[n + 1];
  float acc = 0.f;
  int j = beg + esub;
  bool val0 = j < end;
  float4 rec0 = val0 ? es[j] : make_float4(0.f, 0.f, 0.f, 0.f);
  int s0 = __float_as_int(rec0.x);
  const float4* hp0 = (const float4*)(h_in + s0 * 8);
  float4 hA0 = hp0[0], hB0 = hp0[1];
  while (__ballot(val0)) {
    int j1 = j + 4;
    bool val1 = j1 < end;
    float4 rec1 = val1 ? es[j1] : make_float4(0.f, 0.f, 0.f, 0.f);
    int s1 = __float_as_int(rec1.x);
    const float4* hp1 = (const float4*)(h_in + s1 * 8);
    float4 hA1 = hp1[0], hB1 = hp1[1];
    int t0 = __float_as_int(rec0.y);
    const float4* sp = (const float4*)(embT + t0 * 64 + o * 8);
    float4 sv0 = sp[0], sv1 = sp[1];
    v2f stv[4] = {(v2f){sv0.x, sv0.y}, (v2f){sv0.z, sv0.w},
                  (v2f){sv1.x, sv1.y}, (v2f){sv1.z, sv1.w}};
    v2f hv[4] = {(v2f){hA0.x, hA0.y}, (v2f){hA0.z, hA0.w},
                 (v2f){hB0.x, hB0.y}, (v2f){hB0.z, hB0.w}};
    v2f ef0 = (v2f){rec0.z, rec0.z}, ef1 = (v2f){rec0.w, rec0.w};
    v2f msg = {0.f, 0.f};
#pragma unroll
    for (int p = 0; p < 4; p++) {
      v2f hval = ef0 * rwh0[p] + ef1 * rwh1[p] + rbh[p];
      v2f gval = ef0 * rwg0[p] + ef1 * rwg1[p] + rbg[p];
      msg += hv[p] * vmax0(stv[p] * hval + gval);
    }
    acc += val0 ? (msg.x + msg.y) : 0.f;
    rec0 = rec1; hA0 = hA1; hB0 = hB1; val0 = val1; j = j1;
  }
  acc += __shfl_xor(acc, 8);
  acc += __shfl_xor(acc, 16);
  const float* hn = h_in + n * 8;
  v2f rtv = {0.f, 0.f};
#pragma unroll
  for (int p = 0; p < 4; p++)
    rtv += (v2f){hn[2 * p], hn[2 * p + 1]} * rroot[p];
  float deg = (float)(end - beg);
  float val = fmaxf(rbias + rtv.x + rtv.y + acc / fmaxf(deg, 1.f), 0.f);
  if ((lane & 24) == 0) h_out[n * 8 + o] = val;
}

// ---------------- fused layer 4 (cin=8, cout=64) ----------------------------
// One node per wave, lane = output channel. ALL loads are per-lane VECTOR
// loads (no readfirstlane/s_load path — same-address lanes broadcast from one
// cacheline). 2-stage software pipeline: prefetch next pair's es records
// while computing the current pair; issue next h/emb loads right after.
__global__ __launch_bounds__(256) void layer_l4(
    const int* __restrict__ off, const float4* __restrict__ es,
    const float* __restrict__ h_in, const float* __restrict__ embT,
    const float* __restrict__ wh, const float* __restrict__ bh,
    const float* __restrict__ wg, const float* __restrict__ bg,
    const float* __restrict__ root, const float* __restrict__ bias,
    float* __restrict__ h_out) {
  int lane = threadIdx.x & 63;
  v2f rwh0[4], rwh1[4], rbh[4], rwg0[4], rwg1[4], rbg[4];
#pragma unroll
  for (int p = 0; p < 4; p++) {
    int a = (2 * p) * 64 + lane, b = (2 * p + 1) * 64 + lane;
    rwh0[p] = (v2f){wh[a], wh[b]};
    rwh1[p] = (v2f){wh[512 + a], wh[512 + b]};
    rbh[p]  = (v2f){bh[a], bh[b]};
    rwg0[p] = (v2f){wg[a], wg[b]};
    rwg1[p] = (v2f){wg[512 + a], wg[512 + b]};
    rbg[p]  = (v2f){bg[a], bg[b]};
  }
  int n = (int)(blockIdx.x * 4) + (int)(threadIdx.x >> 6);  // per-lane: vector loads
  int beg = off[n], end = off[n + 1];
  float acc0 = 0.f, acc1 = 0.f;

  auto pair_compute = [&](float4 r0, float4 r1,
                          float4 h00, float4 h01, float4 h10, float4 h11,
                          float4 s00, float4 s01, float4 s10, float4 s11) {
    v2f sv0[4] = {(v2f){s00.x, s00.y}, (v2f){s00.z, s00.w},
                  (v2f){s01.x, s01.y}, (v2f){s01.z, s01.w}};
    v2f sv1[4] = {(v2f){s10.x, s10.y}, (v2f){s10.z, s10.w},
                  (v2f){s11.x, s11.y}, (v2f){s11.z, s11.w}};
    v2f hva[4] = {(v2f){h00.x, h00.y}, (v2f){h00.z, h00.w},
                  (v2f){h01.x, h01.y}, (v2f){h01.z, h01.w}};
    v2f hvb[4] = {(v2f){h10.x, h10.y}, (v2f){h10.z, h10.w},
                  (v2f){h11.x, h11.y}, (v2f){h11.z, h11.w}};
    v2f e00 = (v2f){r0.z, r0.z}, e01 = (v2f){r0.w, r0.w};
    v2f e10 = (v2f){r1.z, r1.z}, e11 = (v2f){r1.w, r1.w};
    v2f m0 = {0.f, 0.f}, m1 = {0.f, 0.f};
#pragma unroll
    for (int p = 0; p < 4; p++) {
      v2f hv0 = e00 * rwh0[p] + e01 * rwh1[p] + rbh[p];
      v2f gv0 = e00 * rwg0[p] + e01 * rwg1[p] + rbg[p];
      m0 += hva[p] * vmax0(sv0[p] * hv0 + gv0);
      v2f hv1 = e10 * rwh0[p] + e11 * rwh1[p] + rbh[p];
      v2f gv1 = e10 * rwg0[p] + e11 * rwg1[p] + rbg[p];
      m1 += hvb[p] * vmax0(sv1[p] * hv1 + gv1);
    }
    acc0 += m0.x + m0.y;
    acc1 += m1.x + m1.y;
  };

  int npair = (end - beg) >> 1;
  int e = beg;
  float4 rC0, rC1, hC00, hC01, hC10, hC11, sC00, sC01, sC10, sC11;
  if (npair > 0) {
    rC0 = es[e]; rC1 = es[e + 1];
    int s0 = __float_as_int(rC0.x), t0 = __float_as_int(rC0.y);
    int s1 = __float_as_int(rC1.x), t1 = __float_as_int(rC1.y);
    const float4* hp0 = (const float4*)(h_in + s0 * 8);
    const float4* hp1 = (const float4*)(h_in + s1 * 8);
    const float4* ep0 = (const float4*)(embT + t0 * 512 + lane * 8);
    const float4* ep1 = (const float4*)(embT + t1 * 512 + lane * 8);
    hC00 = hp0[0]; hC01 = hp0[1]; hC10 = hp1[0]; hC11 = hp1[1];
    sC00 = ep0[0]; sC01 = ep0[1]; sC10 = ep1[0]; sC11 = ep1[1];
  }
  for (int it = 0; it < npair; ++it) {
    bool more = (it + 1) < npair;
    float4 rN0, rN1;
    if (more) { rN0 = es[e + 2]; rN1 = es[e + 3]; }   // independent: issue early
    pair_compute(rC0, rC1, hC00, hC01, hC10, hC11, sC00, sC01, sC10, sC11);
    if (more) {
      int s0 = __float_as_int(rN0.x), t0 = __float_as_int(rN0.y);
      int s1 = __float_as_int(rN1.x), t1 = __float_as_int(rN1.y);
      const float4* hp0 = (const float4*)(h_in + s0 * 8);
      const float4* hp1 = (const float4*)(h_in + s1 * 8);
      const float4* ep0 = (const float4*)(embT + t0 * 512 + lane * 8);
      const float4* ep1 = (const float4*)(embT + t1 * 512 + lane * 8);
      hC00 = hp0[0]; hC01 = hp0[1]; hC10 = hp1[0]; hC11 = hp1[1];
      sC00 = ep0[0]; sC01 = ep0[1]; sC10 = ep1[0]; sC11 = ep1[1];
      rC0 = rN0; rC1 = rN1;
    }
    e += 2;
  }
  // tail: leftover odd edge
  for (int ee = beg + 2 * npair; ee < end; ++ee) {
    float4 r0 = es[ee];
    int s0 = __float_as_int(r0.x), t0 = __float_as_int(r0.y);
    const float4* hp0 = (const float4*)(h_in + s0 * 8);
    float4 a0 = hp0[0], a1 = hp0[1];
    const float4* ep0 = (const float4*)(embT + t0 * 512 + lane * 8);
    float4 s00 = ep0[0], s01 = ep0[1];
    v2f sv0[4] = {(v2f){s00.x, s00.y}, (v2f){s00.z, s00.w},
                  (v2f){s01.x, s01.y}, (v2f){s01.z, s01.w}};
    v2f hva[4] = {(v2f){a0.x, a0.y}, (v2f){a0.z, a0.w},
                  (v2f){a1.x, a1.y}, (v2f){a1.z, a1.w}};
    v2f e00 = (v2f){r0.z, r0.z}, e01 = (v2f){r0.w, r0.w};
    v2f m0 = {0.f, 0.f};
#pragma unroll
    for (int p = 0; p < 4; p++) {
      v2f hv0 = e00 * rwh0[p] + e01 * rwh1[p] + rbh[p];
      v2f gv0 = e00 * rwg0[p] + e01 * rwg1[p] + rbg[p];
      m0 += hva[p] * vmax0(sv0[p] * hv0 + gv0);
    }
    acc0 += m0.x + m0.y;
  }
  float acc = acc0 + acc1;
  float deg = (float)(end - beg);
  // epilogue: root/bias loaded here (not held in registers during the loop)
  const float* hn = h_in + n * 8;
  float rt = bias[lane];
#pragma unroll
  for (int i = 0; i < 8; i++) rt = fmaf(hn[i], root[i * 64 + lane], rt);
  h_out[n * 64 + lane] = fmaxf(rt + acc / fmaxf(deg, 1.f), 0.f);
}

// ---------------- gated pooling, phase 1: 320 blocks ------------------------
__global__ __launch_bounds__(256) void pool1_kernel(
    const float* __restrict__ h4, const int* __restrict__ ct,
    float* __restrict__ pooled, float* __restrict__ pcnt) {
  __shared__ float ss[4][64];
  __shared__ float sc[4];
  int b = blockIdx.x / 20, c = blockIdx.x % 20;
  int base = b * (NN / NBATCH) + c * 64;
  int o = threadIdx.x & 63, sub = threadIdx.x >> 6;
  float sum = 0.f, cnt = 0.f;
  for (int j = sub; j < 64; j += 4) {
    int n = base + j;
    if (ct[n] == 1) { sum += h4[n * 64 + o]; cnt += 1.f; }
  }
  ss[sub][o] = sum;
  if (o == 0) sc[sub] = cnt;
  __syncthreads();
  if (threadIdx.x < 64) {
    float tot = ss[0][o] + ss[1][o] + ss[2][o] + ss[3][o];
    unsafeAtomicAdd(&pooled[b * 64 + o], tot);
    if (o == 0) unsafeAtomicAdd(&pcnt[b], sc[0] + sc[1] + sc[2] + sc[3]);
  }
}

// ---------------- pooling phase 2 + classifier + sigmoid (1 block) ----------
__global__ __launch_bounds__(1024) void pool2_kernel(
    const float* __restrict__ pooled, const float* __restrict__ pcnt,
    const float* __restrict__ clf_w, const float* __restrict__ clf_b,
    float* __restrict__ out) {
  int b = threadIdx.x >> 6, o = threadIdx.x & 63;
  float c = pcnt[b];
  float v = (pooled[b * 64 + o] / fmaxf(c, 1.f)) * clf_w[o];
#pragma unroll
  for (int d = 32; d; d >>= 1) v += __shfl_down(v, d);
  if (o == 0) out[b] = 1.f / (1.f + expf(-(v + clf_b[0])));
}

// ---------------------------------------------------------------------------
extern "C" void kernel_launch(void* const* d_in, const int* in_sizes, int n_in,
                              void* d_out, int out_size, void* d_ws, size_t ws_size,
                              hipStream_t stream) {
  (void)in_sizes; (void)n_in; (void)out_size; (void)ws_size;
  const float* x     = (const float*)d_in[0];
  const int*   eidx  = (const int*)d_in[1];
  const int*   src   = eidx;
  const int*   dst   = eidx + NE;
  const int*   etype = (const int*)d_in[2];
  const float* eattr = (const float*)d_in[3];
  const int*   ct    = (const int*)d_in[4];
  const float *emb[4], *wh[4], *bh[4], *wg[4], *bg[4], *root[4], *bias[4];
  for (int l = 0; l < 4; l++) {
    int b0 = 6 + 7 * l;
    emb[l]  = (const float*)d_in[b0 + 0];
    wh[l]   = (const float*)d_in[b0 + 1];
    bh[l]   = (const float*)d_in[b0 + 2];
    wg[l]   = (const float*)d_in[b0 + 3];
    bg[l]   = (const float*)d_in[b0 + 4];
    root[l] = (const float*)d_in[b0 + 5];
    bias[l] = (const float*)d_in[b0 + 6];
  }
  const float* clf_w = (const float*)d_in[34];
  const float* clf_b = (const float*)d_in[35];
  float* outp = (float*)d_out;

  // workspace layout (floats): ~12.0 MB
  float* ws  = (float*)d_ws;
  int*    off    = (int*)ws;                      // NN+1 (pad 20484)
  float4* es     = (float4*)(ws + 20484);         // NE float4
  float*  hA     = ws + 20484 + 4 * NE;           // 8N
  float*  hB     = hA + 8 * NN;                   // 8N
  float*  h4     = hB + 8 * NN;                   // 64N
  float*  embT1  = h4 + 64 * NN;                  // 36*128
  float*  embT2  = embT1 + 36 * 128;              // 36*64
  float*  embT3  = embT2 + 36 * 64;               // 36*64
  float*  embT4  = embT3 + 36 * 64;               // 36*512
  float*  pooled = embT4 + 36 * 512;              // 16*64
  float*  pcnt   = pooled + 16 * 64;              // 16
  int*    cnt    = (int*)h4;                      // alias (dead until L4)
  int*    cur    = cnt + NN;                      // alias

  // ---- CSR build + emb transpose ----
  hipMemsetAsync(cnt, 0, NN * sizeof(int), stream);
  prep_kernel<<<NE / 256 + 72, 256, 0, stream>>>(dst, cnt, emb[0], emb[1], emb[2], emb[3],
                                                 embT1, embT2, embT3, embT4);
  scan_kernel<<<1, 1024, 0, stream>>>(cnt, off, cur, pooled);
  scatter_kernel<<<NE / 256, 256, 0, stream>>>(src, dst, etype, eattr, cur, es);

  // ---- 4 fused layers ----
  layer_small16<<<NN / 4, 256, 0, stream>>>(off, es, x, embT1,
      wh[0], bh[0], wg[0], bg[0], root[0], bias[0], hA);
  layer_small8<<<NN / 8, 256, 0, stream>>>(off, es, hA, embT2,
      wh[1], bh[1], wg[1], bg[1], root[1], bias[1], hB);
  layer_small8<<<NN / 8, 256, 0, stream>>>(off, es, hB, embT3,
      wh[2], bh[2], wg[2], bg[2], root[2], bias[2], hA);
  layer_l4<<<NN / 4, 256, 0, stream>>>(off, es, hA, embT4,
      wh[3], bh[3], wg[3], bg[3], root[3], bias[3], h4);

  // ---- pooling + classifier + sigmoid ----
  pool1_kernel<<<320, 256, 0, stream>>>(h4, ct, pooled, pcnt);
  pool2_kernel<<<1, 1024, 0, stream>>>(pooled, pcnt, clf_w, clf_b, outp);
}

// Round 9
// 293.489 us; speedup vs baseline: 2.5154x; 1.1445x over previous
//
#include <hip/hip_runtime.h>
#include <math.h>

#define NN 20480
#define NE 327680
#define NBATCH 16

typedef float v2f __attribute__((ext_vector_type(2)));

static __device__ __forceinline__ v2f vmax0(v2f a) {
  v2f r; r.x = fmaxf(a.x, 0.f); r.y = fmaxf(a.y, 0.f); return r;
}
#define VMAX0 vmax0

// ---------------- prep: histogram (1280 blk) + embT4 transpose (72 blk) -----
__global__ __launch_bounds__(256) void prep_kernel(
    const int* __restrict__ dst, int* __restrict__ cnt,
    const float* __restrict__ e4, float* __restrict__ t4) {
  int b = blockIdx.x;
  if (b < NE / 256) {
    int e = b * 256 + threadIdx.x;
    atomicAdd(&cnt[dst[e]], 1);
  } else {
    int idx = (b - NE / 256) * 256 + threadIdx.x;   // 0 .. 18431
    int t = idx >> 9, r = idx & 511, o = r >> 3, i = r & 7;
    t4[idx] = e4[(t << 9) + i * 64 + o];            // [t][i][o] -> [t][o][i]
  }
}

// ------- exclusive scan (1 block); writes off AND cur; zeroes pool ----------
__global__ __launch_bounds__(1024) void scan_kernel(const int* __restrict__ cnt,
                                                    int* __restrict__ off,
                                                    int* __restrict__ cur,
                                                    float* __restrict__ poolz) {
  __shared__ int part[1024];
  int tid = threadIdx.x;
  if (tid < NBATCH * 64 + NBATCH) poolz[tid] = 0.f;
  const int PT = NN / 1024;              // 20 per thread
  int loc[PT];
  int run = 0;
  int base = tid * PT;
#pragma unroll
  for (int k = 0; k < PT; k++) { loc[k] = run; run += cnt[base + k]; }
  part[tid] = run;
  __syncthreads();
  for (int d = 1; d < 1024; d <<= 1) {
    int t = (tid >= d) ? part[tid - d] : 0;
    __syncthreads();
    part[tid] += t;
    __syncthreads();
  }
  int pre = (tid == 0) ? 0 : part[tid - 1];
#pragma unroll
  for (int k = 0; k < PT; k++) {
    off[base + k] = pre + loc[k];
    cur[base + k] = pre + loc[k];
  }
  if (tid == 1023) off[NN] = pre + run;  // == NE
}

__global__ void scatter_kernel(const int* __restrict__ src, const int* __restrict__ dst,
                               const int* __restrict__ etype, const float* __restrict__ eattr,
                               int* __restrict__ cur, float4* __restrict__ es) {
  int e = blockIdx.x * blockDim.x + threadIdx.x;
  if (e >= NE) return;
  int d = dst[e];
  int pos = atomicAdd(&cur[d], 1);
  es[pos] = make_float4(__int_as_float(src[e]), __int_as_float(etype[e]),
                        eattr[2 * e], eattr[2 * e + 1]);
}

// ---------------- fused layer 1 (cin=16, cout=8) — R3 config (298.6 µs total)
// lane = (esub<<4)|(ihalf<<3)|o. LDS semb with odd stride. 2 nodes/wave.
__global__ __launch_bounds__(256) void layer_small16(
    const int* __restrict__ off, const float4* __restrict__ es,
    const float* __restrict__ h_in,
    const float* __restrict__ emb, const float* __restrict__ wh,
    const float* __restrict__ bh, const float* __restrict__ wg,
    const float* __restrict__ bg,
    const float* __restrict__ root, const float* __restrict__ bias,
    float* __restrict__ h_out) {
  constexpr int D = 128;
  constexpr int S = D + 1;               // odd stride spreads banks
  __shared__ float semb[36 * S];
  for (int idx = threadIdx.x; idx < 36 * D; idx += 256) {
    int t = idx / D, io = idx - t * D;
    semb[t * S + io] = emb[idx];
  }
  int lane = threadIdx.x & 63;
  int o = lane & 7;
  int ihalf = (lane >> 3) & 1;
  int esub = lane >> 4;                  // 0..3
  int ibase = ihalf * 8;
  v2f rwh0[4], rwh1[4], rbh[4], rwg0[4], rwg1[4], rbg[4], rroot[4];
#pragma unroll
  for (int p = 0; p < 4; p++) {
    int a = (ibase + 2 * p) * 8 + o, b = (ibase + 2 * p + 1) * 8 + o;
    rwh0[p] = (v2f){wh[a], wh[b]};
    rwh1[p] = (v2f){wh[D + a], wh[D + b]};
    rbh[p]  = (v2f){bh[a], bh[b]};
    rwg0[p] = (v2f){wg[a], wg[b]};
    rwg1[p] = (v2f){wg[D + a], wg[D + b]};
    rbg[p]  = (v2f){bg[a], bg[b]};
    rroot[p] = (v2f){root[a], root[b]};
  }
  float rbias = bias[o];
  __syncthreads();
  int wid = __builtin_amdgcn_readfirstlane(blockIdx.x * 4 + (threadIdx.x >> 6));
  for (int k = 0; k < 2; k++) {
    int n = wid * 2 + k;
    int beg = off[n], end = off[n + 1];
    float acc = 0.f;
    for (int j = beg + esub; j < end; j += 4) {
      float4 rec = es[j];
      int s = __float_as_int(rec.x);
      int t = __float_as_int(rec.y);
      v2f ef0 = (v2f){rec.z, rec.z}, ef1 = (v2f){rec.w, rec.w};
      const float4* hp = (const float4*)(h_in + s * 16 + ibase);
      float4 h0 = hp[0], h1 = hp[1];
      v2f hv[4] = {(v2f){h0.x, h0.y}, (v2f){h0.z, h0.w},
                   (v2f){h1.x, h1.y}, (v2f){h1.z, h1.w}};
      const float* st = &semb[t * S + ibase * 8 + o];
      v2f msg = {0.f, 0.f};
#pragma unroll
      for (int p = 0; p < 4; p++) {
        v2f hval = ef0 * rwh0[p] + ef1 * rwh1[p] + rbh[p];
        v2f gval = ef0 * rwg0[p] + ef1 * rwg1[p] + rbg[p];
        v2f stv = (v2f){st[(2 * p) * 8], st[(2 * p + 1) * 8]};
        msg += hv[p] * VMAX0(stv * hval + gval);
      }
      acc += msg.x + msg.y;
    }
    // xor8 combines i-halves (same edge), xor16/32 combine edges
    acc += __shfl_xor(acc, 8);
    acc += __shfl_xor(acc, 16);
    acc += __shfl_xor(acc, 32);
    const float* hn = h_in + n * 16 + ibase;
    v2f rtv = {0.f, 0.f};
#pragma unroll
    for (int p = 0; p < 4; p++)
      rtv += (v2f){hn[2 * p], hn[2 * p + 1]} * rroot[p];
    float rt = rtv.x + rtv.y;
    rt += __shfl_xor(rt, 8);
    float deg = (float)(end - beg);
    float val = fmaxf(rbias + rt + acc / fmaxf(deg, 1.f), 0.f);
    if (lane < 8) h_out[n * 8 + o] = val;
  }
}

// ---------------- fused layer, cin=8 cout=8 (L2,L3) — R3 config -------------
// lane = (e_sub<<3)|o: 8 edges x 8 outputs. 4 nodes per wave. LDS semb.
__global__ __launch_bounds__(256) void layer_small8(
    const int* __restrict__ off, const float4* __restrict__ es,
    const float* __restrict__ h_in,
    const float* __restrict__ emb, const float* __restrict__ wh,
    const float* __restrict__ bh, const float* __restrict__ wg,
    const float* __restrict__ bg,
    const float* __restrict__ root, const float* __restrict__ bias,
    float* __restrict__ h_out) {
  constexpr int D = 64;
  constexpr int S = D + 1;
  __shared__ float semb[36 * S];
  for (int idx = threadIdx.x; idx < 36 * D; idx += 256) {
    int t = idx / D, io = idx - t * D;
    semb[t * S + io] = emb[idx];
  }
  int lane = threadIdx.x & 63;
  int o = lane & 7, esub = lane >> 3;
  v2f rwh0[4], rwh1[4], rbh[4], rwg0[4], rwg1[4], rbg[4], rroot[4];
#pragma unroll
  for (int p = 0; p < 4; p++) {
    int a = (2 * p) * 8 + o, b = (2 * p + 1) * 8 + o;
    rwh0[p] = (v2f){wh[a], wh[b]};
    rwh1[p] = (v2f){wh[D + a], wh[D + b]};
    rbh[p]  = (v2f){bh[a], bh[b]};
    rwg0[p] = (v2f){wg[a], wg[b]};
    rwg1[p] = (v2f){wg[D + a], wg[D + b]};
    rbg[p]  = (v2f){bg[a], bg[b]};
    rroot[p] = (v2f){root[a], root[b]};
  }
  float rbias = bias[o];
  __syncthreads();
  int wid = __builtin_amdgcn_readfirstlane(blockIdx.x * 4 + (threadIdx.x >> 6));
  for (int k = 0; k < 4; k++) {
    int n = wid * 4 + k;
    int beg = off[n], end = off[n + 1];
    float acc = 0.f;
    for (int j = beg + esub; j < end; j += 8) {
      float4 rec = es[j];
      int s = __float_as_int(rec.x);
      int t = __float_as_int(rec.y);
      v2f ef0 = (v2f){rec.z, rec.z}, ef1 = (v2f){rec.w, rec.w};
      const float4* hp = (const float4*)(h_in + s * 8);
      float4 h0 = hp[0], h1 = hp[1];
      v2f hv[4] = {(v2f){h0.x, h0.y}, (v2f){h0.z, h0.w},
                   (v2f){h1.x, h1.y}, (v2f){h1.z, h1.w}};
      const float* st = &semb[t * S + o];
      v2f msg = {0.f, 0.f};
#pragma unroll
      for (int p = 0; p < 4; p++) {
        v2f hval = ef0 * rwh0[p] + ef1 * rwh1[p] + rbh[p];
        v2f gval = ef0 * rwg0[p] + ef1 * rwg1[p] + rbg[p];
        v2f stv = (v2f){st[(2 * p) * 8], st[(2 * p + 1) * 8]};
        msg += hv[p] * VMAX0(stv * hval + gval);
      }
      acc += msg.x + msg.y;
    }
    acc += __shfl_xor(acc, 8);
    acc += __shfl_xor(acc, 16);
    acc += __shfl_xor(acc, 32);
    float deg = (float)(end - beg);
    const float* hn = h_in + n * 8;
    v2f rtv = {0.f, 0.f};
#pragma unroll
    for (int p = 0; p < 4; p++)
      rtv += (v2f){hn[2 * p], hn[2 * p + 1]} * rroot[p];
    float val = fmaxf(rbias + rtv.x + rtv.y + acc / fmaxf(deg, 1.f), 0.f);
    if (lane < 8) h_out[n * 8 + o] = val;
  }
}

// ---------------- fused layer 4 (cin=8, cout=64) — best measured (50.0 µs) --
// One node per wave, lane = out channel. Edge record + h row wave-uniform
// (readfirstlane -> s_loads); emb transposed: 2x dwordx4 per edge. Unroll-2.
__global__ __launch_bounds__(256) void layer_l4(
    const int* __restrict__ off, const float4* __restrict__ es,
    const float* __restrict__ h_in, const float* __restrict__ embT,
    const float* __restrict__ wh, const float* __restrict__ bh,
    const float* __restrict__ wg, const float* __restrict__ bg,
    const float* __restrict__ root, const float* __restrict__ bias,
    float* __restrict__ h_out) {
  int lane = threadIdx.x & 63;
  v2f rwh0[4], rwh1[4], rbh[4], rwg0[4], rwg1[4], rbg[4], rroot[4];
#pragma unroll
  for (int p = 0; p < 4; p++) {
    int a = (2 * p) * 64 + lane, b = (2 * p + 1) * 64 + lane;
    rwh0[p] = (v2f){wh[a], wh[b]};
    rwh1[p] = (v2f){wh[512 + a], wh[512 + b]};
    rbh[p]  = (v2f){bh[a], bh[b]};
    rwg0[p] = (v2f){wg[a], wg[b]};
    rwg1[p] = (v2f){wg[512 + a], wg[512 + b]};
    rbg[p]  = (v2f){bg[a], bg[b]};
    rroot[p] = (v2f){root[a], root[b]};
  }
  float rbias = bias[lane];
  int n = __builtin_amdgcn_readfirstlane((int)(blockIdx.x * 4) + (int)(threadIdx.x >> 6));
  int beg = off[n], end = off[n + 1];
  float acc0 = 0.f, acc1 = 0.f;
  int e = beg;
  for (; e + 2 <= end; e += 2) {
    float4 r0 = es[e], r1 = es[e + 1];            // uniform -> s_loads
    int s0 = __float_as_int(r0.x), t0 = __float_as_int(r0.y);
    int s1 = __float_as_int(r1.x), t1 = __float_as_int(r1.y);
    const float4* hp0 = (const float4*)(h_in + s0 * 8);
    const float4* hp1 = (const float4*)(h_in + s1 * 8);
    float4 a0 = hp0[0], a1 = hp0[1];
    float4 b0 = hp1[0], b1 = hp1[1];
    const float4* ep0 = (const float4*)(embT + t0 * 512 + lane * 8);
    const float4* ep1 = (const float4*)(embT + t1 * 512 + lane * 8);
    float4 s00 = ep0[0], s01 = ep0[1];
    float4 s10 = ep1[0], s11 = ep1[1];
    v2f sv0[4] = {(v2f){s00.x, s00.y}, (v2f){s00.z, s00.w},
                  (v2f){s01.x, s01.y}, (v2f){s01.z, s01.w}};
    v2f sv1[4] = {(v2f){s10.x, s10.y}, (v2f){s10.z, s10.w},
                  (v2f){s11.x, s11.y}, (v2f){s11.z, s11.w}};
    v2f hva[4] = {(v2f){a0.x, a0.y}, (v2f){a0.z, a0.w},
                  (v2f){a1.x, a1.y}, (v2f){a1.z, a1.w}};
    v2f hvb[4] = {(v2f){b0.x, b0.y}, (v2f){b0.z, b0.w},
                  (v2f){b1.x, b1.y}, (v2f){b1.z, b1.w}};
    v2f e00 = (v2f){r0.z, r0.z}, e01 = (v2f){r0.w, r0.w};
    v2f e10 = (v2f){r1.z, r1.z}, e11 = (v2f){r1.w, r1.w};
    v2f m0 = {0.f, 0.f}, m1 = {0.f, 0.f};
#pragma unroll
    for (int p = 0; p < 4; p++) {
      v2f hv0 = e00 * rwh0[p] + e01 * rwh1[p] + rbh[p];
      v2f gv0 = e00 * rwg0[p] + e01 * rwg1[p] + rbg[p];
      m0 += hva[p] * VMAX0(sv0[p] * hv0 + gv0);
      v2f hv1 = e10 * rwh0[p] + e11 * rwh1[p] + rbh[p];
      v2f gv1 = e10 * rwg0[p] + e11 * rwg1[p] + rbg[p];
      m1 += hvb[p] * VMAX0(sv1[p] * hv1 + gv1);
    }
    acc0 += m0.x + m0.y;
    acc1 += m1.x + m1.y;
  }
  if (e < end) {
    float4 r0 = es[e];
    int s0 = __float_as_int(r0.x), t0 = __float_as_int(r0.y);
    const float4* hp0 = (const float4*)(h_in + s0 * 8);
    float4 a0 = hp0[0], a1 = hp0[1];
    const float4* ep0 = (const float4*)(embT + t0 * 512 + lane * 8);
    float4 s00 = ep0[0], s01 = ep0[1];
    v2f sv0[4] = {(v2f){s00.x, s00.y}, (v2f){s00.z, s00.w},
                  (v2f){s01.x, s01.y}, (v2f){s01.z, s01.w}};
    v2f hva[4] = {(v2f){a0.x, a0.y}, (v2f){a0.z, a0.w},
                  (v2f){a1.x, a1.y}, (v2f){a1.z, a1.w}};
    v2f e00 = (v2f){r0.z, r0.z}, e01 = (v2f){r0.w, r0.w};
    v2f m0 = {0.f, 0.f};
#pragma unroll
    for (int p = 0; p < 4; p++) {
      v2f hv0 = e00 * rwh0[p] + e01 * rwh1[p] + rbh[p];
      v2f gv0 = e00 * rwg0[p] + e01 * rwg1[p] + rbg[p];
      m0 += hva[p] * VMAX0(sv0[p] * hv0 + gv0);
    }
    acc0 += m0.x + m0.y;
  }
  float acc = acc0 + acc1;
  float deg = (float)(end - beg);
  const float* hn = h_in + n * 8;
  v2f rtv = {0.f, 0.f};
#pragma unroll
  for (int p = 0; p < 4; p++)
    rtv += (v2f){hn[2 * p], hn[2 * p + 1]} * rroot[p];
  h_out[n * 64 + lane] = fmaxf(rbias + rtv.x + rtv.y + acc / fmaxf(deg, 1.f), 0.f);
}

// ---------------- gated pooling, phase 1: 320 blocks ------------------------
__global__ __launch_bounds__(256) void pool1_kernel(
    const float* __restrict__ h4, const int* __restrict__ ct,
    float* __restrict__ pooled, float* __restrict__ pcnt) {
  __shared__ float ss[4][64];
  __shared__ float sc[4];
  int b = blockIdx.x / 20, c = blockIdx.x % 20;
  int base = b * (NN / NBATCH) + c * 64;
  int o = threadIdx.x & 63, sub = threadIdx.x >> 6;
  float sum = 0.f, cnt = 0.f;
  for (int j = sub; j < 64; j += 4) {
    int n = base + j;
    if (ct[n] == 1) { sum += h4[n * 64 + o]; cnt += 1.f; }
  }
  ss[sub][o] = sum;
  if (o == 0) sc[sub] = cnt;
  __syncthreads();
  if (threadIdx.x < 64) {
    float tot = ss[0][o] + ss[1][o] + ss[2][o] + ss[3][o];
    unsafeAtomicAdd(&pooled[b * 64 + o], tot);
    if (o == 0) unsafeAtomicAdd(&pcnt[b], sc[0] + sc[1] + sc[2] + sc[3]);
  }
}

// ---------------- pooling phase 2 + classifier + sigmoid (1 block) ----------
__global__ __launch_bounds__(1024) void pool2_kernel(
    const float* __restrict__ pooled, const float* __restrict__ pcnt,
    const float* __restrict__ clf_w, const float* __restrict__ clf_b,
    float* __restrict__ out) {
  int b = threadIdx.x >> 6, o = threadIdx.x & 63;
  float c = pcnt[b];
  float v = (pooled[b * 64 + o] / fmaxf(c, 1.f)) * clf_w[o];
#pragma unroll
  for (int d = 32; d; d >>= 1) v += __shfl_down(v, d);
  if (o == 0) out[b] = 1.f / (1.f + expf(-(v + clf_b[0])));
}

// ---------------------------------------------------------------------------
extern "C" void kernel_launch(void* const* d_in, const int* in_sizes, int n_in,
                              void* d_out, int out_size, void* d_ws, size_t ws_size,
                              hipStream_t stream) {
  (void)in_sizes; (void)n_in; (void)out_size; (void)ws_size;
  const float* x     = (const float*)d_in[0];
  const int*   eidx  = (const int*)d_in[1];
  const int*   src   = eidx;
  const int*   dst   = eidx + NE;
  const int*   etype = (const int*)d_in[2];
  const float* eattr = (const float*)d_in[3];
  const int*   ct    = (const int*)d_in[4];
  const float *emb[4], *wh[4], *bh[4], *wg[4], *bg[4], *root[4], *bias[4];
  for (int l = 0; l < 4; l++) {
    int b0 = 6 + 7 * l;
    emb[l]  = (const float*)d_in[b0 + 0];
    wh[l]   = (const float*)d_in[b0 + 1];
    bh[l]   = (const float*)d_in[b0 + 2];
    wg[l]   = (const float*)d_in[b0 + 3];
    bg[l]   = (const float*)d_in[b0 + 4];
    root[l] = (const float*)d_in[b0 + 5];
    bias[l] = (const float*)d_in[b0 + 6];
  }
  const float* clf_w = (const float*)d_in[34];
  const float* clf_b = (const float*)d_in[35];
  float* outp = (float*)d_out;

  // workspace layout (floats): ~11.96 MB
  float* ws  = (float*)d_ws;
  int*    off    = (int*)ws;                      // NN+1 (pad 20484)
  float4* es     = (float4*)(ws + 20484);         // NE float4
  float*  hA     = ws + 20484 + 4 * NE;           // 8N
  float*  hB     = hA + 8 * NN;                   // 8N
  float*  h4     = hB + 8 * NN;                   // 64N
  float*  embT4  = h4 + 64 * NN;                  // 36*512
  float*  pooled = embT4 + 36 * 512;              // 16*64
  float*  pcnt   = pooled + 16 * 64;              // 16
  int*    cnt    = (int*)h4;                      // alias (dead until L4)
  int*    cur    = cnt + NN;                      // alias

  // ---- CSR build + embT4 transpose (4 dispatches) ----
  hipMemsetAsync(cnt, 0, NN * sizeof(int), stream);
  prep_kernel<<<NE / 256 + 72, 256, 0, stream>>>(dst, cnt, emb[3], embT4);
  scan_kernel<<<1, 1024, 0, stream>>>(cnt, off, cur, pooled);
  scatter_kernel<<<NE / 256, 256, 0, stream>>>(src, dst, etype, eattr, cur, es);

  // ---- 4 fused layers (best-measured configs) ----
  layer_small16<<<2560, 256, 0, stream>>>(off, es, x,
      emb[0], wh[0], bh[0], wg[0], bg[0], root[0], bias[0], hA);
  layer_small8<<<1280, 256, 0, stream>>>(off, es, hA,
      emb[1], wh[1], bh[1], wg[1], bg[1], root[1], bias[1], hB);
  layer_small8<<<1280, 256, 0, stream>>>(off, es, hB,
      emb[2], wh[2], bh[2], wg[2], bg[2], root[2], bias[2], hA);
  layer_l4<<<NN / 4, 256, 0, stream>>>(off, es, hA, embT4,
      wh[3], bh[3], wg[3], bg[3], root[3], bias[3], h4);

  // ---- pooling + classifier + sigmoid ----
  pool1_kernel<<<320, 256, 0, stream>>>(h4, ct, pooled, pcnt);
  pool2_kernel<<<1, 1024, 0, stream>>>(pooled, pcnt, clf_w, clf_b, outp);
}